// Round 6
// baseline (61.266 us; speedup 1.0000x reference)
//
#include <hip/hip_runtime.h>
#include <hip/hip_bf16.h>

// out[d,t] = (sum_j exp(s[t,j]) * u[j,d]) / (sum_j exp(s[t,j]))
// Fused exp-GEMM, B staged in LDS once per block.
// R6: 256 blocks x 512 threads (8 waves = 2/SIMD -> 256-VGPR budget, no spill;
// R5's 1024-thread block forced a 128-VGPR cap and spilled sbuf to scratch:
// VGPR=64, WRITE_SIZE 105MB). Single generation; each wave computes TWO
// 16-row tiles so every B ds_read_b128 feeds 2 MFMAs and per-wave MLP doubles.

constexpr int T_DIM = 65536;
constexpr int J_DIM = 512;
constexpr int D_DIM = 128;
constexpr int KK_STEPS = J_DIM / 32;   // 16
constexpr int NFRAG = 8;               // 8 N-fragments covering D=128
constexpr int PF_DEPTH = 4;            // s-load prefetch depth (iterations)
constexpr int BP_ELEMS = KK_STEPS * NFRAG * 64;   // s16x8 elements = 8192 (128KB)

typedef __attribute__((ext_vector_type(4))) float  f32x4;
typedef __attribute__((ext_vector_type(8))) short  s16x8;
typedef __attribute__((ext_vector_type(8))) __bf16 bf16x8;

__device__ __forceinline__ short f2bf_rne(float f) {
    unsigned u = __builtin_bit_cast(unsigned, f);
    u += 0x7fffu + ((u >> 16) & 1u);   // round-to-nearest-even
    return (short)(u >> 16);
}

__global__ __launch_bounds__(256) void prep_b(const float* __restrict__ u,
                                              short* __restrict__ bp) {
    int tid = blockIdx.x * blockDim.x + threadIdx.x;
    if (tid >= BP_ELEMS) return;
    int l  = tid & 63;
    int nf = (tid >> 6) & (NFRAG - 1);
    int kk = tid >> 9;
    int d  = nf * 16 + (l & 15);
    int k0 = kk * 32 + 8 * (l >> 4);
    s16x8 o;
#pragma unroll
    for (int i = 0; i < 8; ++i)
        o[i] = f2bf_rne(u[(size_t)(k0 + i) * D_DIM + d]);
    *reinterpret_cast<s16x8*>(bp + (size_t)tid * 8) = o;
}

__global__ __launch_bounds__(512, 2) void c2q_main(const float* __restrict__ sm,
                                                   const short* __restrict__ bp,
                                                   float* __restrict__ out) {
    __shared__ s16x8 bsh[BP_ELEMS];    // [kk][nf][lane] — 131072 bytes

    const int tid  = threadIdx.x;
    const int l    = tid & 63;
    const int w    = tid >> 6;        // wave 0..7
    const int lmod = l & 15;
    const int lh   = l >> 4;          // 0..3
    const int r0a  = blockIdx.x * 256 + w * 16;   // tile A first t-row
    const int r0b  = r0a + 128;                   // tile B first t-row

    // A-fragment sources: lane holds row r0+lmod, k = kk*32 + 8*lh + i.
    const float* spA = sm + (size_t)(r0a + lmod) * J_DIM + lh * 8;
    const float* spB = sm + (size_t)(r0b + lmod) * J_DIM + lh * 8;

    // ---- s-prefetch prologue (overlaps HBM latency with the LDS fill) ----
    f32x4 sbufA[PF_DEPTH][2], sbufB[PF_DEPTH][2];
#pragma unroll
    for (int p = 0; p < PF_DEPTH; ++p) {
        sbufA[p][0] = *reinterpret_cast<const f32x4*>(spA + p * 32);
        sbufA[p][1] = *reinterpret_cast<const f32x4*>(spA + p * 32 + 4);
        sbufB[p][0] = *reinterpret_cast<const f32x4*>(spB + p * 32);
        sbufB[p][1] = *reinterpret_cast<const f32x4*>(spB + p * 32 + 4);
    }

    // ---- one-time B fill: 512 threads x 16 iters x 16B (reg-staged) ----
    {
        const s16x8* bps = reinterpret_cast<const s16x8*>(bp);
#pragma unroll
        for (int it = 0; it < BP_ELEMS / 512; ++it)
            bsh[it * 512 + tid] = bps[it * 512 + tid];
    }
    __syncthreads();

    f32x4 accA[NFRAG], accB[NFRAG];
#pragma unroll
    for (int nf = 0; nf < NFRAG; ++nf) {
        accA[nf] = (f32x4){0.f, 0.f, 0.f, 0.f};
        accB[nf] = (f32x4){0.f, 0.f, 0.f, 0.f};
    }
    float denA = 0.f, denB = 0.f;

#pragma unroll
    for (int kk = 0; kk < KK_STEPS; ++kk) {
        f32x4 a0 = sbufA[kk & (PF_DEPTH - 1)][0];
        f32x4 a1 = sbufA[kk & (PF_DEPTH - 1)][1];
        f32x4 b0 = sbufB[kk & (PF_DEPTH - 1)][0];
        f32x4 b1 = sbufB[kk & (PF_DEPTH - 1)][1];
        if (kk + PF_DEPTH < KK_STEPS) {
            sbufA[kk & (PF_DEPTH - 1)][0] =
                *reinterpret_cast<const f32x4*>(spA + (kk + PF_DEPTH) * 32);
            sbufA[kk & (PF_DEPTH - 1)][1] =
                *reinterpret_cast<const f32x4*>(spA + (kk + PF_DEPTH) * 32 + 4);
            sbufB[kk & (PF_DEPTH - 1)][0] =
                *reinterpret_cast<const f32x4*>(spB + (kk + PF_DEPTH) * 32);
            sbufB[kk & (PF_DEPTH - 1)][1] =
                *reinterpret_cast<const f32x4*>(spB + (kk + PF_DEPTH) * 32 + 4);
        }
        float ea0 = __expf(a0[0]), ea1 = __expf(a0[1]);
        float ea2 = __expf(a0[2]), ea3 = __expf(a0[3]);
        float ea4 = __expf(a1[0]), ea5 = __expf(a1[1]);
        float ea6 = __expf(a1[2]), ea7 = __expf(a1[3]);
        float eb0 = __expf(b0[0]), eb1 = __expf(b0[1]);
        float eb2 = __expf(b0[2]), eb3 = __expf(b0[3]);
        float eb4 = __expf(b1[0]), eb5 = __expf(b1[1]);
        float eb6 = __expf(b1[2]), eb7 = __expf(b1[3]);
        denA += ((ea0 + ea1) + (ea2 + ea3)) + ((ea4 + ea5) + (ea6 + ea7));
        denB += ((eb0 + eb1) + (eb2 + eb3)) + ((eb4 + eb5) + (eb6 + eb7));
        s16x8 pa, pb;
        pa[0] = f2bf_rne(ea0); pa[1] = f2bf_rne(ea1);
        pa[2] = f2bf_rne(ea2); pa[3] = f2bf_rne(ea3);
        pa[4] = f2bf_rne(ea4); pa[5] = f2bf_rne(ea5);
        pa[6] = f2bf_rne(ea6); pa[7] = f2bf_rne(ea7);
        pb[0] = f2bf_rne(eb0); pb[1] = f2bf_rne(eb1);
        pb[2] = f2bf_rne(eb2); pb[3] = f2bf_rne(eb3);
        pb[4] = f2bf_rne(eb4); pb[5] = f2bf_rne(eb5);
        pb[6] = f2bf_rne(eb6); pb[7] = f2bf_rne(eb7);
        bf16x8 avA = __builtin_bit_cast(bf16x8, pa);
        bf16x8 avB = __builtin_bit_cast(bf16x8, pb);
#pragma unroll
        for (int nf = 0; nf < NFRAG; ++nf) {
            bf16x8 bv = __builtin_bit_cast(bf16x8, bsh[(kk * NFRAG + nf) * 64 + l]);
            accA[nf] = __builtin_amdgcn_mfma_f32_16x16x32_bf16(avA, bv, accA[nf], 0, 0, 0);
            accB[nf] = __builtin_amdgcn_mfma_f32_16x16x32_bf16(avB, bv, accB[nf], 0, 0, 0);
        }
        __builtin_amdgcn_sched_barrier(0);   // keep per-iteration structure
    }

    // den(l) holds row lmod's partial over k-chunk lh: reduce the 4 chunks.
    denA += __shfl_xor(denA, 16, 64);
    denA += __shfl_xor(denA, 32, 64);
    denB += __shfl_xor(denB, 16, 64);
    denB += __shfl_xor(denB, 32, 64);
    // C/D layout: col = lane&15 (-> d), row = 4*(lane>>4)+reg (-> t).
    float invA[4], invB[4];
#pragma unroll
    for (int r = 0; r < 4; ++r) {
        invA[r] = 1.0f / __shfl(denA, 4 * lh + r, 64);
        invB[r] = 1.0f / __shfl(denB, 4 * lh + r, 64);
    }

#pragma unroll
    for (int nf = 0; nf < NFRAG; ++nf) {
        f32x4 va, vb;
#pragma unroll
        for (int r = 0; r < 4; ++r) {
            va[r] = accA[nf][r] * invA[r];
            vb[r] = accB[nf][r] * invB[r];
        }
        *reinterpret_cast<f32x4*>(out + (size_t)(nf * 16 + lmod) * T_DIM
                                  + r0a + 4 * lh) = va;
        *reinterpret_cast<f32x4*>(out + (size_t)(nf * 16 + lmod) * T_DIM
                                  + r0b + 4 * lh) = vb;
    }
}

extern "C" void kernel_launch(void* const* d_in, const int* in_sizes, int n_in,
                              void* d_out, int out_size, void* d_ws, size_t ws_size,
                              hipStream_t stream) {
    const float* u = (const float*)d_in[0];   // (1, 512, 128) fp32
    const float* s = (const float*)d_in[1];   // (65536, 512) fp32
    float* out = (float*)d_out;               // (128, 65536) fp32
    short* bp = (short*)d_ws;                 // 131072 bytes used

    prep_b<<<(BP_ELEMS + 255) / 256, 256, 0, stream>>>(u, bp);
    c2q_main<<<T_DIM / 256, 512, 0, stream>>>(s, bp, out);
}

// Round 7
// 56.785 us; speedup vs baseline: 1.0789x; 1.0789x over previous
//
#include <hip/hip_runtime.h>
#include <hip/hip_bf16.h>

// out[d,t] = (sum_j exp(s[t,j]) * u[j,d]) / (sum_j exp(s[t,j]))
// Fused exp-GEMM, B staged in LDS once per block.
// R7: single-generation 1024-thread layout (256 blocks x 16 waves, 1 tile/wave)
// with __attribute__((amdgpu_waves_per_eu(4,4))) so the allocator gets the full
// 128-VGPR budget. R5 failed because the compiler targeted 8 waves/EU (64 VGPR,
// impossible anyway with 128KB LDS) and spilled sbuf to scratch (WRITE 105MB);
// R6's two-tile variant spilled likewise (WRITE 96MB). PF_DEPTH=2 (16 VGPR)
// keeps 64KB/CU of s-loads in flight — still >> the ~11KB BDP.

constexpr int T_DIM = 65536;
constexpr int J_DIM = 512;
constexpr int D_DIM = 128;
constexpr int KK_STEPS = J_DIM / 32;   // 16
constexpr int NFRAG = 8;               // 8 N-fragments covering D=128
constexpr int PF_DEPTH = 2;            // s-load prefetch depth (iterations)
constexpr int BP_ELEMS = KK_STEPS * NFRAG * 64;   // s16x8 elements = 8192 (128KB)

typedef __attribute__((ext_vector_type(4))) float  f32x4;
typedef __attribute__((ext_vector_type(8))) short  s16x8;
typedef __attribute__((ext_vector_type(8))) __bf16 bf16x8;

__device__ __forceinline__ short f2bf_rne(float f) {
    unsigned u = __builtin_bit_cast(unsigned, f);
    u += 0x7fffu + ((u >> 16) & 1u);   // round-to-nearest-even
    return (short)(u >> 16);
}

__global__ __launch_bounds__(256) void prep_b(const float* __restrict__ u,
                                              short* __restrict__ bp) {
    int tid = blockIdx.x * blockDim.x + threadIdx.x;
    if (tid >= BP_ELEMS) return;
    int l  = tid & 63;
    int nf = (tid >> 6) & (NFRAG - 1);
    int kk = tid >> 9;
    int d  = nf * 16 + (l & 15);
    int k0 = kk * 32 + 8 * (l >> 4);
    s16x8 o;
#pragma unroll
    for (int i = 0; i < 8; ++i)
        o[i] = f2bf_rne(u[(size_t)(k0 + i) * D_DIM + d]);
    *reinterpret_cast<s16x8*>(bp + (size_t)tid * 8) = o;
}

__global__ __launch_bounds__(1024)
__attribute__((amdgpu_waves_per_eu(4, 4)))
void c2q_main(const float* __restrict__ sm,
              const short* __restrict__ bp,
              float* __restrict__ out) {
    __shared__ s16x8 bsh[BP_ELEMS];    // [kk][nf][lane] — 131072 bytes

    const int tid  = threadIdx.x;
    const int l    = tid & 63;
    const int w    = tid >> 6;        // wave 0..15
    const int lmod = l & 15;
    const int lh   = l >> 4;          // 0..3
    const int r0   = blockIdx.x * 256 + w * 16;  // this wave's first t-row

    // A-fragment source: lane holds row r0+lmod, k = kk*32 + 8*lh + i.
    const float* sp = sm + (size_t)(r0 + lmod) * J_DIM + lh * 8;

    // ---- s-prefetch prologue (issue before the LDS fill so HBM overlaps) ----
    f32x4 sbuf[PF_DEPTH][2];
#pragma unroll
    for (int p = 0; p < PF_DEPTH; ++p) {
        sbuf[p][0] = *reinterpret_cast<const f32x4*>(sp + p * 32);
        sbuf[p][1] = *reinterpret_cast<const f32x4*>(sp + p * 32 + 4);
    }

    // ---- one-time B fill: 1024 threads x 8 iters x 16B (reg-staged) ----
    {
        const s16x8* bps = reinterpret_cast<const s16x8*>(bp);
#pragma unroll
        for (int it = 0; it < BP_ELEMS / 1024; ++it)
            bsh[it * 1024 + tid] = bps[it * 1024 + tid];
    }
    __syncthreads();

    f32x4 acc[NFRAG];
#pragma unroll
    for (int nf = 0; nf < NFRAG; ++nf) acc[nf] = (f32x4){0.f, 0.f, 0.f, 0.f};
    float den = 0.f;

#pragma unroll
    for (int kk = 0; kk < KK_STEPS; ++kk) {
        f32x4 s0 = sbuf[kk & (PF_DEPTH - 1)][0];
        f32x4 s1 = sbuf[kk & (PF_DEPTH - 1)][1];
        if (kk + PF_DEPTH < KK_STEPS) {
            sbuf[kk & (PF_DEPTH - 1)][0] =
                *reinterpret_cast<const f32x4*>(sp + (kk + PF_DEPTH) * 32);
            sbuf[kk & (PF_DEPTH - 1)][1] =
                *reinterpret_cast<const f32x4*>(sp + (kk + PF_DEPTH) * 32 + 4);
        }
        float e0 = __expf(s0[0]), e1 = __expf(s0[1]);
        float e2 = __expf(s0[2]), e3 = __expf(s0[3]);
        float e4 = __expf(s1[0]), e5 = __expf(s1[1]);
        float e6 = __expf(s1[2]), e7 = __expf(s1[3]);
        den += ((e0 + e1) + (e2 + e3)) + ((e4 + e5) + (e6 + e7));
        s16x8 a;
        a[0] = f2bf_rne(e0); a[1] = f2bf_rne(e1);
        a[2] = f2bf_rne(e2); a[3] = f2bf_rne(e3);
        a[4] = f2bf_rne(e4); a[5] = f2bf_rne(e5);
        a[6] = f2bf_rne(e6); a[7] = f2bf_rne(e7);
        bf16x8 av = __builtin_bit_cast(bf16x8, a);
#pragma unroll
        for (int nf = 0; nf < NFRAG; ++nf) {
            bf16x8 bv = __builtin_bit_cast(bf16x8, bsh[(kk * NFRAG + nf) * 64 + l]);
            acc[nf] = __builtin_amdgcn_mfma_f32_16x16x32_bf16(av, bv, acc[nf], 0, 0, 0);
        }
        __builtin_amdgcn_sched_barrier(0);   // keep per-iteration structure
    }

    // den(l) holds row lmod's partial over k-chunk lh: reduce the 4 chunks.
    den += __shfl_xor(den, 16, 64);
    den += __shfl_xor(den, 32, 64);
    // C/D layout: col = lane&15 (-> d), row = 4*(lane>>4)+reg (-> t).
    float inv[4];
#pragma unroll
    for (int r = 0; r < 4; ++r)
        inv[r] = 1.0f / __shfl(den, 4 * lh + r, 64);

#pragma unroll
    for (int nf = 0; nf < NFRAG; ++nf) {
        f32x4 v;
#pragma unroll
        for (int r = 0; r < 4; ++r) v[r] = acc[nf][r] * inv[r];
        *reinterpret_cast<f32x4*>(out + (size_t)(nf * 16 + lmod) * T_DIM
                                  + r0 + 4 * lh) = v;
    }
}

extern "C" void kernel_launch(void* const* d_in, const int* in_sizes, int n_in,
                              void* d_out, int out_size, void* d_ws, size_t ws_size,
                              hipStream_t stream) {
    const float* u = (const float*)d_in[0];   // (1, 512, 128) fp32
    const float* s = (const float*)d_in[1];   // (65536, 512) fp32
    float* out = (float*)d_out;               // (128, 65536) fp32
    short* bp = (short*)d_ws;                 // 131072 bytes used

    prep_b<<<(BP_ELEMS + 255) / 256, 256, 0, stream>>>(u, bp);
    c2q_main<<<T_DIM / 256, 1024, 0, stream>>>(s, bp, out);
}

// Round 8
// 38.724 us; speedup vs baseline: 1.5822x; 1.4664x over previous
//
#include <hip/hip_runtime.h>
#include <hip/hip_bf16.h>

// out[d,t] = (sum_j exp(s[t,j]) * u[j,d]) / (sum_j exp(s[t,j]))
// Fused exp-GEMM, B staged in LDS once per block.
// R8: exact R4 structure (512 blocks x 512 threads, one 16-row tile per wave,
// depth-4 register prefetch — the proven no-spill 40.6us shape) with prep_b
// FOLDED INTO the block prologue: each block gathers/packs B fragments
// directly from u (256KB, L2-resident) instead of reading a pre-packed bp.
// Removes the separate tiny kernel launch + graph serialization gap.
// R5/R6/R7 lesson: 1024-thread or two-tile variants always spill (VGPR=64,
// WRITE_SIZE 93-105MB) regardless of waves_per_eu hints — don't go back.

constexpr int T_DIM = 65536;
constexpr int J_DIM = 512;
constexpr int D_DIM = 128;
constexpr int KK_STEPS = J_DIM / 32;   // 16
constexpr int NFRAG = 8;               // 8 N-fragments covering D=128
constexpr int PF_DEPTH = 4;            // s-load prefetch depth (iterations)
constexpr int BP_ELEMS = KK_STEPS * NFRAG * 64;   // s16x8 elements = 8192 (128KB)

typedef __attribute__((ext_vector_type(4))) float  f32x4;
typedef __attribute__((ext_vector_type(8))) short  s16x8;
typedef __attribute__((ext_vector_type(8))) __bf16 bf16x8;

__device__ __forceinline__ short f2bf_rne(float f) {
    unsigned u = __builtin_bit_cast(unsigned, f);
    u += 0x7fffu + ((u >> 16) & 1u);   // round-to-nearest-even
    return (short)(u >> 16);
}

__global__ __launch_bounds__(512, 2) void c2q_main(const float* __restrict__ sm,
                                                   const float* __restrict__ u,
                                                   float* __restrict__ out) {
    __shared__ s16x8 bsh[BP_ELEMS];    // [kk][nf][lane] — 131072 bytes

    const int tid  = threadIdx.x;
    const int l    = tid & 63;
    const int w    = tid >> 6;        // wave 0..7
    const int lmod = l & 15;
    const int lh   = l >> 4;          // 0..3
    const int r0   = blockIdx.x * 128 + w * 16;  // this wave's first t-row

    // A-fragment source: lane holds row r0+lmod, k = kk*32 + 8*lh + i.
    const float* sp = sm + (size_t)(r0 + lmod) * J_DIM + lh * 8;

    // ---- s-prefetch prologue (HBM latency overlaps the gather/fill) ----
    f32x4 sbuf[PF_DEPTH][2];
#pragma unroll
    for (int p = 0; p < PF_DEPTH; ++p) {
        sbuf[p][0] = *reinterpret_cast<const f32x4*>(sp + p * 32);
        sbuf[p][1] = *reinterpret_cast<const f32x4*>(sp + p * 32 + 4);
    }

    // ---- B gather-fill straight from u (L2-resident, 256KB):
    // element e: lane=e&63, nf=(e>>6)&7, kk=e>>9;
    //   d = nf*16 + (e&15), k0 = kk*32 + 8*((e>>4)&3); pack 8 bf16.
#pragma unroll 4
    for (int it = 0; it < BP_ELEMS / 512; ++it) {
        int e  = it * 512 + tid;
        int d  = ((e >> 6) & (NFRAG - 1)) * 16 + (e & 15);
        int k0 = (e >> 9) * 32 + 8 * ((e >> 4) & 3);
        const float* up = u + (size_t)k0 * D_DIM + d;
        s16x8 o;
#pragma unroll
        for (int i = 0; i < 8; ++i)
            o[i] = f2bf_rne(up[(size_t)i * D_DIM]);
        bsh[e] = o;
    }
    __syncthreads();

    f32x4 acc[NFRAG];
#pragma unroll
    for (int nf = 0; nf < NFRAG; ++nf) acc[nf] = (f32x4){0.f, 0.f, 0.f, 0.f};
    float den = 0.f;

#pragma unroll
    for (int kk = 0; kk < KK_STEPS; ++kk) {
        f32x4 s0 = sbuf[kk & (PF_DEPTH - 1)][0];
        f32x4 s1 = sbuf[kk & (PF_DEPTH - 1)][1];
        if (kk + PF_DEPTH < KK_STEPS) {
            sbuf[kk & (PF_DEPTH - 1)][0] =
                *reinterpret_cast<const f32x4*>(sp + (kk + PF_DEPTH) * 32);
            sbuf[kk & (PF_DEPTH - 1)][1] =
                *reinterpret_cast<const f32x4*>(sp + (kk + PF_DEPTH) * 32 + 4);
        }
        float e0 = __expf(s0[0]), e1 = __expf(s0[1]);
        float e2 = __expf(s0[2]), e3 = __expf(s0[3]);
        float e4 = __expf(s1[0]), e5 = __expf(s1[1]);
        float e6 = __expf(s1[2]), e7 = __expf(s1[3]);
        den += ((e0 + e1) + (e2 + e3)) + ((e4 + e5) + (e6 + e7));
        s16x8 a;
        a[0] = f2bf_rne(e0); a[1] = f2bf_rne(e1);
        a[2] = f2bf_rne(e2); a[3] = f2bf_rne(e3);
        a[4] = f2bf_rne(e4); a[5] = f2bf_rne(e5);
        a[6] = f2bf_rne(e6); a[7] = f2bf_rne(e7);
        bf16x8 av = __builtin_bit_cast(bf16x8, a);
#pragma unroll
        for (int nf = 0; nf < NFRAG; ++nf) {
            bf16x8 bv = __builtin_bit_cast(bf16x8, bsh[(kk * NFRAG + nf) * 64 + l]);
            acc[nf] = __builtin_amdgcn_mfma_f32_16x16x32_bf16(av, bv, acc[nf], 0, 0, 0);
        }
        __builtin_amdgcn_sched_barrier(0);   // keep per-iteration structure
    }

    // den(l) holds row lmod's partial over k-chunk lh: reduce the 4 chunks.
    den += __shfl_xor(den, 16, 64);
    den += __shfl_xor(den, 32, 64);
    // C/D layout: col = lane&15 (-> d), row = 4*(lane>>4)+reg (-> t).
    float inv[4];
#pragma unroll
    for (int r = 0; r < 4; ++r)
        inv[r] = 1.0f / __shfl(den, 4 * lh + r, 64);

#pragma unroll
    for (int nf = 0; nf < NFRAG; ++nf) {
        f32x4 v;
#pragma unroll
        for (int r = 0; r < 4; ++r) v[r] = acc[nf][r] * inv[r];
        *reinterpret_cast<f32x4*>(out + (size_t)(nf * 16 + lmod) * T_DIM
                                  + r0 + 4 * lh) = v;
    }
}

extern "C" void kernel_launch(void* const* d_in, const int* in_sizes, int n_in,
                              void* d_out, int out_size, void* d_ws, size_t ws_size,
                              hipStream_t stream) {
    const float* u = (const float*)d_in[0];   // (1, 512, 128) fp32
    const float* s = (const float*)d_in[1];   // (65536, 512) fp32
    float* out = (float*)d_out;               // (128, 65536) fp32

    c2q_main<<<T_DIM / 128, 512, 0, stream>>>(s, u, out);
}

// Round 9
// 36.750 us; speedup vs baseline: 1.6671x; 1.0537x over previous
//
#include <hip/hip_runtime.h>
#include <hip/hip_bf16.h>

// out[d,t] = (sum_j exp(s[t,j]) * u[j,d]) / (sum_j exp(s[t,j]))
// Fused exp-GEMM, B staged in LDS once per block.
// R9: persistent single-generation grid — 256 blocks x 512 threads (1 block/CU),
// each block runs TWO 128-row panels SEQUENTIALLY (same registers reused, so
// none of the R5/R6/R7 concurrent-state spills). The depth-6 rotating prefetch
// is indexed by global iteration g = p*16+kk, slot = g%6: panel-0's tail
// iterations prefetch panel-1's first rows, so the HBM s-stream never drains
// across the panel boundary, B is filled once, and there is no block-switch
// bubble. R8 paid these twice (two generations).

constexpr int T_DIM = 65536;
constexpr int J_DIM = 512;
constexpr int D_DIM = 128;
constexpr int KK_STEPS = J_DIM / 32;   // 16
constexpr int NFRAG = 8;               // 8 N-fragments covering D=128
constexpr int PF_DEPTH = 6;            // s-load prefetch depth (iterations)
constexpr int BP_ELEMS = KK_STEPS * NFRAG * 64;   // s16x8 elements = 8192 (128KB)

typedef __attribute__((ext_vector_type(4))) float  f32x4;
typedef __attribute__((ext_vector_type(8))) short  s16x8;
typedef __attribute__((ext_vector_type(8))) __bf16 bf16x8;

__device__ __forceinline__ short f2bf_rne(float f) {
    unsigned u = __builtin_bit_cast(unsigned, f);
    u += 0x7fffu + ((u >> 16) & 1u);   // round-to-nearest-even
    return (short)(u >> 16);
}

__global__ __launch_bounds__(512, 2) void c2q_main(const float* __restrict__ sm,
                                                   const float* __restrict__ u,
                                                   float* __restrict__ out) {
    __shared__ s16x8 bsh[BP_ELEMS];    // [kk][nf][lane] — 131072 bytes

    const int tid  = threadIdx.x;
    const int l    = tid & 63;
    const int w    = tid >> 6;        // wave 0..7
    const int lmod = l & 15;
    const int lh   = l >> 4;          // 0..3
    const int r0   = blockIdx.x * 256 + w * 16;  // panel-0 first t-row

    // A-fragment sources: lane holds row r0+lmod, k = kk*32 + 8*lh + i.
    const float* sp0 = sm + (size_t)(r0 + lmod) * J_DIM + lh * 8;
    const float* sp1 = sp0 + 128 * J_DIM;        // panel-1 (r0+128)

    // ---- prologue: prefetch global iterations 0..5 (panel 0, kk 0..5) ----
    f32x4 sbuf[PF_DEPTH][2];
#pragma unroll
    for (int p = 0; p < PF_DEPTH; ++p) {
        sbuf[p][0] = *reinterpret_cast<const f32x4*>(sp0 + p * 32);
        sbuf[p][1] = *reinterpret_cast<const f32x4*>(sp0 + p * 32 + 4);
    }

    // ---- B gather-fill straight from u (L2-resident, 256KB), once ----
#pragma unroll 4
    for (int it = 0; it < BP_ELEMS / 512; ++it) {
        int e  = it * 512 + tid;
        int d  = ((e >> 6) & (NFRAG - 1)) * 16 + (e & 15);
        int k0 = (e >> 9) * 32 + 8 * ((e >> 4) & 3);
        const float* up = u + (size_t)k0 * D_DIM + d;
        s16x8 o;
#pragma unroll
        for (int i = 0; i < 8; ++i)
            o[i] = f2bf_rne(up[(size_t)i * D_DIM]);
        bsh[e] = o;
    }
    __syncthreads();

#pragma unroll
    for (int p = 0; p < 2; ++p) {
        const int rp = r0 + p * 128;

        f32x4 acc[NFRAG];
#pragma unroll
        for (int nf = 0; nf < NFRAG; ++nf) acc[nf] = (f32x4){0.f, 0.f, 0.f, 0.f};
        float den = 0.f;

#pragma unroll
        for (int kk = 0; kk < KK_STEPS; ++kk) {
            const int g    = p * KK_STEPS + kk;      // global iteration 0..31
            const int slot = g % PF_DEPTH;           // compile-time constant
            f32x4 s0 = sbuf[slot][0];
            f32x4 s1 = sbuf[slot][1];
            // refill this slot for global iteration g+6 (possibly next panel)
            if (g + PF_DEPTH < 2 * KK_STEPS) {
                const int   f  = g + PF_DEPTH;
                const float* b = (f < KK_STEPS) ? sp0 : sp1;
                const int   tk = f & (KK_STEPS - 1);
                sbuf[slot][0] = *reinterpret_cast<const f32x4*>(b + tk * 32);
                sbuf[slot][1] = *reinterpret_cast<const f32x4*>(b + tk * 32 + 4);
            }
            float e0 = __expf(s0[0]), e1 = __expf(s0[1]);
            float e2 = __expf(s0[2]), e3 = __expf(s0[3]);
            float e4 = __expf(s1[0]), e5 = __expf(s1[1]);
            float e6 = __expf(s1[2]), e7 = __expf(s1[3]);
            den += ((e0 + e1) + (e2 + e3)) + ((e4 + e5) + (e6 + e7));
            s16x8 a;
            a[0] = f2bf_rne(e0); a[1] = f2bf_rne(e1);
            a[2] = f2bf_rne(e2); a[3] = f2bf_rne(e3);
            a[4] = f2bf_rne(e4); a[5] = f2bf_rne(e5);
            a[6] = f2bf_rne(e6); a[7] = f2bf_rne(e7);
            bf16x8 av = __builtin_bit_cast(bf16x8, a);
#pragma unroll
            for (int nf = 0; nf < NFRAG; ++nf) {
                bf16x8 bv = __builtin_bit_cast(bf16x8, bsh[(kk * NFRAG + nf) * 64 + l]);
                acc[nf] = __builtin_amdgcn_mfma_f32_16x16x32_bf16(av, bv, acc[nf], 0, 0, 0);
            }
            __builtin_amdgcn_sched_barrier(0);   // keep per-iteration structure
        }

        // den(l) holds row lmod's partial over k-chunk lh: reduce the 4 chunks.
        den += __shfl_xor(den, 16, 64);
        den += __shfl_xor(den, 32, 64);
        // C/D layout: col = lane&15 (-> d), row = 4*(lane>>4)+reg (-> t).
        float inv[4];
#pragma unroll
        for (int r = 0; r < 4; ++r)
            inv[r] = 1.0f / __shfl(den, 4 * lh + r, 64);

#pragma unroll
        for (int nf = 0; nf < NFRAG; ++nf) {
            f32x4 v;
#pragma unroll
            for (int r = 0; r < 4; ++r) v[r] = acc[nf][r] * inv[r];
            *reinterpret_cast<f32x4*>(out + (size_t)(nf * 16 + lmod) * T_DIM
                                      + rp + 4 * lh) = v;
        }
    }
}

extern "C" void kernel_launch(void* const* d_in, const int* in_sizes, int n_in,
                              void* d_out, int out_size, void* d_ws, size_t ws_size,
                              hipStream_t stream) {
    const float* u = (const float*)d_in[0];   // (1, 512, 128) fp32
    const float* s = (const float*)d_in[1];   // (65536, 512) fp32
    float* out = (float*)d_out;               // (128, 65536) fp32

    c2q_main<<<T_DIM / 256, 512, 0, stream>>>(s, u, out);
}

// Round 10
// 36.186 us; speedup vs baseline: 1.6931x; 1.0156x over previous
//
#include <hip/hip_runtime.h>
#include <hip/hip_bf16.h>

// out[d,t] = (sum_j exp(s[t,j]) * u[j,d]) / (sum_j exp(s[t,j]))
// Fused exp-GEMM, B staged in LDS once per block.
// R10 = R9 structure (256 blocks x 512 threads, 1 block/CU, two sequential
// 128-row panels, depth-6 cross-panel rotating prefetch) with two in-loop
// changes:
//  1) sched_barrier(0) every TWO iterations (was every one) — lets the
//     scheduler overlap iteration pairs (ds_reads/exp of g+1 under g's
//     vmcnt wait) while still pinning the rotating prefetch (worst-case
//     sink = 1 iteration, effective depth 5).
//  2) A-pack via v_cvt_pk_bf16_f32 inline asm (4 ops, RNE) instead of
//     ~36 manual bit-op VALU instructions.

constexpr int T_DIM = 65536;
constexpr int J_DIM = 512;
constexpr int D_DIM = 128;
constexpr int KK_STEPS = J_DIM / 32;   // 16
constexpr int NFRAG = 8;               // 8 N-fragments covering D=128
constexpr int PF_DEPTH = 6;            // s-load prefetch depth (iterations)
constexpr int BP_ELEMS = KK_STEPS * NFRAG * 64;   // s16x8 elements = 8192 (128KB)

typedef __attribute__((ext_vector_type(4))) float  f32x4;
typedef __attribute__((ext_vector_type(4))) int    i32x4;
typedef __attribute__((ext_vector_type(8))) short  s16x8;
typedef __attribute__((ext_vector_type(8))) __bf16 bf16x8;

__device__ __forceinline__ short f2bf_rne(float f) {
    unsigned u = __builtin_bit_cast(unsigned, f);
    u += 0x7fffu + ((u >> 16) & 1u);   // round-to-nearest-even
    return (short)(u >> 16);
}

__device__ __forceinline__ int cvt_pk_bf16(float lo, float hi) {
    int r;
    asm("v_cvt_pk_bf16_f32 %0, %1, %2" : "=v"(r) : "v"(lo), "v"(hi));
    return r;   // r[15:0]=bf16(lo), r[31:16]=bf16(hi), RNE
}

__global__ __launch_bounds__(512, 2) void c2q_main(const float* __restrict__ sm,
                                                   const float* __restrict__ u,
                                                   float* __restrict__ out) {
    __shared__ s16x8 bsh[BP_ELEMS];    // [kk][nf][lane] — 131072 bytes

    const int tid  = threadIdx.x;
    const int l    = tid & 63;
    const int w    = tid >> 6;        // wave 0..7
    const int lmod = l & 15;
    const int lh   = l >> 4;          // 0..3
    const int r0   = blockIdx.x * 256 + w * 16;  // panel-0 first t-row

    // A-fragment sources: lane holds row r0+lmod, k = kk*32 + 8*lh + i.
    const float* sp0 = sm + (size_t)(r0 + lmod) * J_DIM + lh * 8;
    const float* sp1 = sp0 + 128 * J_DIM;        // panel-1 (r0+128)

    // ---- prologue: prefetch global iterations 0..5 (panel 0, kk 0..5) ----
    f32x4 sbuf[PF_DEPTH][2];
#pragma unroll
    for (int p = 0; p < PF_DEPTH; ++p) {
        sbuf[p][0] = *reinterpret_cast<const f32x4*>(sp0 + p * 32);
        sbuf[p][1] = *reinterpret_cast<const f32x4*>(sp0 + p * 32 + 4);
    }

    // ---- B gather-fill straight from u (L2-resident, 256KB), once ----
#pragma unroll 4
    for (int it = 0; it < BP_ELEMS / 512; ++it) {
        int e  = it * 512 + tid;
        int d  = ((e >> 6) & (NFRAG - 1)) * 16 + (e & 15);
        int k0 = (e >> 9) * 32 + 8 * ((e >> 4) & 3);
        const float* up = u + (size_t)k0 * D_DIM + d;
        s16x8 o;
#pragma unroll
        for (int i = 0; i < 8; ++i)
            o[i] = f2bf_rne(up[(size_t)i * D_DIM]);
        bsh[e] = o;
    }
    __syncthreads();

#pragma unroll
    for (int p = 0; p < 2; ++p) {
        const int rp = r0 + p * 128;

        f32x4 acc[NFRAG];
#pragma unroll
        for (int nf = 0; nf < NFRAG; ++nf) acc[nf] = (f32x4){0.f, 0.f, 0.f, 0.f};
        float den = 0.f;

#pragma unroll
        for (int kk = 0; kk < KK_STEPS; ++kk) {
            const int g    = p * KK_STEPS + kk;      // global iteration 0..31
            const int slot = g % PF_DEPTH;           // compile-time constant
            f32x4 s0 = sbuf[slot][0];
            f32x4 s1 = sbuf[slot][1];
            // refill this slot for global iteration g+6 (possibly next panel)
            if (g + PF_DEPTH < 2 * KK_STEPS) {
                const int   f  = g + PF_DEPTH;
                const float* b = (f < KK_STEPS) ? sp0 : sp1;
                const int   tk = f & (KK_STEPS - 1);
                sbuf[slot][0] = *reinterpret_cast<const f32x4*>(b + tk * 32);
                sbuf[slot][1] = *reinterpret_cast<const f32x4*>(b + tk * 32 + 4);
            }
            float e0 = __expf(s0[0]), e1 = __expf(s0[1]);
            float e2 = __expf(s0[2]), e3 = __expf(s0[3]);
            float e4 = __expf(s1[0]), e5 = __expf(s1[1]);
            float e6 = __expf(s1[2]), e7 = __expf(s1[3]);
            den += ((e0 + e1) + (e2 + e3)) + ((e4 + e5) + (e6 + e7));
            i32x4 aw;
            aw[0] = cvt_pk_bf16(e0, e1);
            aw[1] = cvt_pk_bf16(e2, e3);
            aw[2] = cvt_pk_bf16(e4, e5);
            aw[3] = cvt_pk_bf16(e6, e7);
            bf16x8 av = __builtin_bit_cast(bf16x8, aw);
#pragma unroll
            for (int nf = 0; nf < NFRAG; ++nf) {
                bf16x8 bv = __builtin_bit_cast(bf16x8, bsh[(kk * NFRAG + nf) * 64 + l]);
                acc[nf] = __builtin_amdgcn_mfma_f32_16x16x32_bf16(av, bv, acc[nf], 0, 0, 0);
            }
            if (g & 1) __builtin_amdgcn_sched_barrier(0);  // fence every 2 iters
        }

        // den(l) holds row lmod's partial over k-chunk lh: reduce the 4 chunks.
        den += __shfl_xor(den, 16, 64);
        den += __shfl_xor(den, 32, 64);
        // C/D layout: col = lane&15 (-> d), row = 4*(lane>>4)+reg (-> t).
        float inv[4];
#pragma unroll
        for (int r = 0; r < 4; ++r)
            inv[r] = 1.0f / __shfl(den, 4 * lh + r, 64);

#pragma unroll
        for (int nf = 0; nf < NFRAG; ++nf) {
            f32x4 v;
#pragma unroll
            for (int r = 0; r < 4; ++r) v[r] = acc[nf][r] * inv[r];
            *reinterpret_cast<f32x4*>(out + (size_t)(nf * 16 + lmod) * T_DIM
                                      + rp + 4 * lh) = v;
        }
    }
}

extern "C" void kernel_launch(void* const* d_in, const int* in_sizes, int n_in,
                              void* d_out, int out_size, void* d_ws, size_t ws_size,
                              hipStream_t stream) {
    const float* u = (const float*)d_in[0];   // (1, 512, 128) fp32
    const float* s = (const float*)d_in[1];   // (65536, 512) fp32
    float* out = (float*)d_out;               // (128, 65536) fp32

    c2q_main<<<T_DIM / 256, 512, 0, stream>>>(s, u, out);
}